// Round 16
// baseline (364.421 us; speedup 1.0000x reference)
//
#include <hip/hip_runtime.h>
#include <hip/hip_bf16.h>
#include <math.h>

#define EMB 32
#define HID 64
#define PAT 8

#define BSH   9                 // nodes per bucket = 512
#define NBMAX 256               // max buckets supported (N <= 131072; src fits 17 bits)
#define CHUNK 4096              // edges per partition block

typedef __attribute__((ext_vector_type(8))) short short8v;   // 8 bf16 = 4 VGPRs
typedef __attribute__((ext_vector_type(16))) float f32x16;   // MFMA 32x32 accumulator

union Frag {
    short8v s8;
    uint4 u4;
    __hip_bfloat162 h2[4];
    __hip_bfloat16 h[8];
    unsigned short us[8];
};

__device__ __forceinline__ float bf_lo(unsigned v) { return __uint_as_float(v << 16); }
__device__ __forceinline__ float bf_hi(unsigned v) { return __uint_as_float(v & 0xFFFF0000u); }
__device__ __forceinline__ unsigned pack_bf2(float a, float b) {
    __hip_bfloat16 ba = __float2bfloat16(a), bb = __float2bfloat16(b);
    return ((unsigned)*(unsigned short*)&bb << 16) | *(unsigned short*)&ba;
}

// ---------------- pass 0: per-block LDS bucket histogram ----------------
__global__ __launch_bounds__(256) void bucket_hist_kernel(
    const int* __restrict__ dst, int* __restrict__ btot, int e) {
    __shared__ int cnt[NBMAX];
    int t = threadIdx.x;
    for (int k = t; k < NBMAX; k += 256) cnt[k] = 0;
    __syncthreads();
    int e0 = blockIdx.x * CHUNK;
    int ec = min(CHUNK, e - e0);
    for (int k = t; k < ec; k += 256)
        atomicAdd(&cnt[dst[e0 + k] >> BSH], 1);
    __syncthreads();
    for (int k = t; k < NBMAX; k += 256)
        if (cnt[k]) atomicAdd(&btot[k], cnt[k]);
}

// one block: exclusive scan of bucket totals -> bbase (197 entries), bcur
__global__ void scan_buckets_kernel(const int* __restrict__ btot, int* __restrict__ bbase,
                                    int* __restrict__ bcur, int nbuck, int e) {
    __shared__ int s[256];
    int t = threadIdx.x;
    int v = (t < nbuck) ? btot[t] : 0;
    s[t] = v;
    __syncthreads();
    for (int off = 1; off < 256; off <<= 1) {
        int u = (t >= off) ? s[t - off] : 0;
        __syncthreads();
        s[t] += u;
        __syncthreads();
    }
    if (t < nbuck) {
        int ex = s[t] - v;
        bbase[t] = ex;
        bcur[t]  = ex;
    }
    if (t == 0) bbase[nbuck] = e;
}

// ---------------- pass A: LDS-staged partition; output packed (dlocal<<17 | src) ----------------
__global__ __launch_bounds__(256) void partition_kernel(
    const int* __restrict__ ei, int* __restrict__ bcur,
    unsigned* __restrict__ pairs, int e) {
    __shared__ int cnt[NBMAX];
    __shared__ int scn[NBMAX];
    __shared__ int loff[NBMAX];
    __shared__ int base[NBMAX];
    __shared__ int2 stg[CHUNK];
    int t = threadIdx.x;
    int e0 = blockIdx.x * CHUNK;
    int ecnt = min(CHUNK, e - e0);

    int2 ed[CHUNK / 256];
#pragma unroll
    for (int j = 0; j < CHUNK / 256; ++j) {
        int k = t + j * 256;
        if (k < ecnt) { ed[j].x = ei[e0 + k]; ed[j].y = ei[e + e0 + k]; }
    }

    for (int k = t; k < NBMAX; k += 256) cnt[k] = 0;
    __syncthreads();
#pragma unroll
    for (int j = 0; j < CHUNK / 256; ++j)
        if (t + j * 256 < ecnt) atomicAdd(&cnt[ed[j].y >> BSH], 1);
    __syncthreads();
    int c = cnt[t];
    scn[t] = c;
    __syncthreads();
    for (int off = 1; off < 256; off <<= 1) {
        int u = (t >= off) ? scn[t - off] : 0;
        __syncthreads();
        scn[t] += u;
        __syncthreads();
    }
    int ex = scn[t] - c;
    __syncthreads();
    scn[t] = ex;
    loff[t] = ex;
    base[t] = c ? atomicAdd(&bcur[t], c) : 0;
    __syncthreads();
#pragma unroll
    for (int j = 0; j < CHUNK / 256; ++j)
        if (t + j * 256 < ecnt) {
            int pos = atomicAdd(&loff[ed[j].y >> BSH], 1);
            stg[pos] = ed[j];
        }
    __syncthreads();
    for (int k = t; k < ecnt; k += 256) {
        int2 pr = stg[k];
        int b = pr.y >> BSH;
        unsigned pk = ((unsigned)(pr.y & ((1 << BSH) - 1)) << 17) | (unsigned)pr.x;
        pairs[base[b] + (k - scn[b])] = pk;
    }
}

// ---------------- pass B: per-bucket count+scan+scatter; emits row_ptr/rend/dinv/csr_src ----------------
__global__ __launch_bounds__(256) void bucket_scatter_kernel(
    const int* __restrict__ bbase, const unsigned* __restrict__ pairs,
    int* __restrict__ csr_src, int* __restrict__ row_ptr, int* __restrict__ rend,
    float* __restrict__ dinv, int n) {
    __shared__ int cnt[1 << BSH];
    __shared__ int scn[256];
    __shared__ int cur[1 << BSH];
    int b = blockIdx.x;
    int n0 = b << BSH;
    int nn = min(1 << BSH, n - n0);
    int t = threadIdx.x;
    cnt[t] = 0; cnt[t + 256] = 0;
    __syncthreads();
    int p0 = bbase[b], p1 = bbase[b + 1];
    for (int k = p0 + t; k < p1; k += 256)
        atomicAdd(&cnt[pairs[k] >> 17], 1);
    __syncthreads();
    int ca = cnt[2 * t], cb = cnt[2 * t + 1];
    int c2 = ca + cb;
    scn[t] = c2;
    __syncthreads();
    for (int off = 1; off < 256; off <<= 1) {
        int u = (t >= off) ? scn[t - off] : 0;
        __syncthreads();
        scn[t] += u;
        __syncthreads();
    }
    int ex2 = scn[t] - c2;
    int ea = p0 + ex2;
    int eb = ea + ca;
    if (2 * t < nn) {
        row_ptr[n0 + 2 * t] = ea;
        rend[n0 + 2 * t]    = ea + ca;
        dinv[n0 + 2 * t]    = rsqrtf(1.0f + (float)ca);
        cur[2 * t] = ea;
    }
    if (2 * t + 1 < nn) {
        row_ptr[n0 + 2 * t + 1] = eb;
        rend[n0 + 2 * t + 1]    = eb + cb;
        dinv[n0 + 2 * t + 1]    = rsqrtf(1.0f + (float)cb);
        cur[2 * t + 1] = eb;
    }
    __syncthreads();
    for (int k = p0 + t; k < p1; k += 256) {
        unsigned v = pairs[k];
        int pos = atomicAdd(&cur[v >> 17], 1);
        csr_src[pos] = (int)(v & 0x1FFFFu);
    }
}

// ---------------- pack Wf1 into MFMA fragment order (bf16) ----------------
__global__ void prep_wf1_kernel(const float* __restrict__ Wf1, __hip_bfloat16* __restrict__ wfrag) {
    int gid = blockIdx.x * blockDim.x + threadIdx.x;
    if (gid >= 10 * 512) return;
    int f = gid >> 9;
    int rem = gid & 511;
    int l = rem >> 3;
    int e = rem & 7;
    int c = f >> 1;
    int t = f & 1;
    int k = c * 16 + ((l >> 5) << 3) + e;
    int n = (l & 31) + (t << 5);
    float v = (k < HID + PAT) ? Wf1[k * 64 + n] : 0.0f;
    wfrag[gid] = __float2bfloat16(v);
}

// ---------------- pack W2 into MFMA B-fragment order (bf16): 8 frags ----------------
__global__ void prep_w2_kernel(const float* __restrict__ W2, __hip_bfloat16* __restrict__ w2frag) {
    int gid = blockIdx.x * blockDim.x + threadIdx.x;
    if (gid >= 8 * 512) return;
    int f = gid >> 9;
    int rem = gid & 511;
    int l = rem >> 3;
    int e = rem & 7;
    int c = f >> 1;
    int t = f & 1;
    int k = c * 16 + ((l >> 5) << 3) + e;
    int n = (l & 31) + (t << 5);
    w2frag[gid] = __float2bfloat16(W2[k * 64 + n]);
}

// ---------------- pack epilogue weights ----------------
__global__ void prep_epi_kernel(const float* __restrict__ bf1, const float* __restrict__ Wf2,
                                float4* __restrict__ wepi) {
    int t = threadIdx.x;
    if (t >= 32) return;
    int r = t >> 1, half = t & 1;
    int ch = (r & 3) + 8 * (r >> 2) + 4 * half;
    wepi[t] = make_float4(bf1[ch], Wf2[ch], bf1[ch + 32], Wf2[ch + 32]);
}

// ---------------- layer-1 matmul: hbs1 = bf16((emb @ W1) * dinv) ----------------
__global__ __launch_bounds__(256) void mm1_kernel(
    const float* __restrict__ emb, const float* __restrict__ W1,
    const float* __restrict__ dinv,
    __hip_bfloat16* __restrict__ hbs, int n) {
    __shared__ float w[EMB * HID];  // 8 KB
    int t = threadIdx.x;
    for (int k = t; k < EMB * HID; k += 256) w[k] = W1[k];
    __syncthreads();
    int wave = t >> 6, lane = t & 63;
    int i = blockIdx.x * 4 + wave;
    if (i >= n) return;
    float e = (lane < EMB) ? emb[i * EMB + lane] : 0.0f;
    float acc = 0.0f;
#pragma unroll
    for (int k = 0; k < EMB; ++k) {
        float ek = __shfl(e, k, 64);
        acc += ek * w[k * HID + lane];
    }
    hbs[(size_t)i * HID + lane] = __float2bfloat16(acc * dinv[i]);
}

// ======== 2-edges-per-instruction gather core, software-pipelined indices ========
// 16 edges/iter (8 per parity half, 8 row-loads in flight per lane = r13's proven
// VGPR-32 depth). Next iteration's 8 index loads are issued BEFORE the current
// rows are consumed, so the waitcnt on rows overlaps the next index fetch:
// per-iter chain ~= L_row instead of L_idx + L_row.
__device__ __forceinline__ float2 gather_row2(
    const int* __restrict__ csr_src, const __hip_bfloat16* __restrict__ hb,
    int i, int e, int end, int halfe, int lp2) {
    float s0 = 0.0f, s1 = 0.0f;
    int k = e + halfe;
    int a0 = 0, a1 = 0, a2 = 0, a3 = 0, a4 = 0, a5 = 0, a6 = 0, a7 = 0;
    bool have = (k + 14 < end);
    if (have) {
        a0 = csr_src[k];      a1 = csr_src[k + 2];
        a2 = csr_src[k + 4];  a3 = csr_src[k + 6];
        a4 = csr_src[k + 8];  a5 = csr_src[k + 10];
        a6 = csr_src[k + 12]; a7 = csr_src[k + 14];
    }
    while (have) {
        int nk = k + 16;
        bool nhave = (nk + 14 < end);
        int b0 = 0, b1 = 0, b2 = 0, b3 = 0, b4 = 0, b5 = 0, b6 = 0, b7 = 0;
        if (nhave) {                       // prefetch next chunk's indices
            b0 = csr_src[nk];      b1 = csr_src[nk + 2];
            b2 = csr_src[nk + 4];  b3 = csr_src[nk + 6];
            b4 = csr_src[nk + 8];  b5 = csr_src[nk + 10];
            b6 = csr_src[nk + 12]; b7 = csr_src[nk + 14];
        }
        unsigned r0 = *(const unsigned*)&hb[(size_t)a0 * HID + lp2];
        unsigned r1 = *(const unsigned*)&hb[(size_t)a1 * HID + lp2];
        unsigned r2 = *(const unsigned*)&hb[(size_t)a2 * HID + lp2];
        unsigned r3 = *(const unsigned*)&hb[(size_t)a3 * HID + lp2];
        unsigned r4 = *(const unsigned*)&hb[(size_t)a4 * HID + lp2];
        unsigned r5 = *(const unsigned*)&hb[(size_t)a5 * HID + lp2];
        unsigned r6 = *(const unsigned*)&hb[(size_t)a6 * HID + lp2];
        unsigned r7 = *(const unsigned*)&hb[(size_t)a7 * HID + lp2];
        s0 += ((bf_lo(r0) + bf_lo(r1)) + (bf_lo(r2) + bf_lo(r3))) +
              ((bf_lo(r4) + bf_lo(r5)) + (bf_lo(r6) + bf_lo(r7)));
        s1 += ((bf_hi(r0) + bf_hi(r1)) + (bf_hi(r2) + bf_hi(r3))) +
              ((bf_hi(r4) + bf_hi(r5)) + (bf_hi(r6) + bf_hi(r7)));
        a0 = b0; a1 = b1; a2 = b2; a3 = b3;
        a4 = b4; a5 = b5; a6 = b6; a7 = b7;
        k = nk; have = nhave;
    }
    for (; k + 6 < end; k += 8) {
        int c0 = csr_src[k], c1 = csr_src[k + 2], c2 = csr_src[k + 4], c3 = csr_src[k + 6];
        unsigned r0 = *(const unsigned*)&hb[(size_t)c0 * HID + lp2];
        unsigned r1 = *(const unsigned*)&hb[(size_t)c1 * HID + lp2];
        unsigned r2 = *(const unsigned*)&hb[(size_t)c2 * HID + lp2];
        unsigned r3 = *(const unsigned*)&hb[(size_t)c3 * HID + lp2];
        s0 += (bf_lo(r0) + bf_lo(r1)) + (bf_lo(r2) + bf_lo(r3));
        s1 += (bf_hi(r0) + bf_hi(r1)) + (bf_hi(r2) + bf_hi(r3));
    }
    for (; k < end; k += 2) {
        unsigned r0 = *(const unsigned*)&hb[(size_t)csr_src[k] * HID + lp2];
        s0 += bf_lo(r0);
        s1 += bf_hi(r0);
    }
    s0 += __shfl_xor(s0, 32, 64);
    s1 += __shfl_xor(s1, 32, 64);
    unsigned sv = *(const unsigned*)&hb[(size_t)i * HID + lp2];
    s0 += bf_lo(sv);
    s1 += bf_hi(sv);
    return make_float2(s0, s1);
}

// ---------------- fused gather(L1) + MFMA mm2: 32 rows/block ----------------
__global__ __launch_bounds__(256) void gather_mm2_kernel(
    const int* __restrict__ row_ptr, const int* __restrict__ rend,
    const int* __restrict__ csr_src, const float* __restrict__ dinv,
    const __hip_bfloat16* __restrict__ hbs1, const __hip_bfloat16* __restrict__ w2frag,
    const float* __restrict__ b1, __hip_bfloat16* __restrict__ hbs2, int n) {
    __shared__ __attribute__((aligned(16))) unsigned short x1s[32 * 64];  // 4 KB
    int t = threadIdx.x;
    int lane = t & 63;
    int wv = t >> 6;
    int halfe = lane >> 5;
    int lp = lane & 31;
    int lp2 = lp * 2;
    int n0 = blockIdx.x << 5;
    float2 b1v = *(const float2*)&b1[lp2];

    for (int rr = 0; rr < 8; ++rr) {
        int row = wv * 8 + rr;
        int i = n0 + row;
        unsigned pk = 0;
        if (i < n) {
            float2 s = gather_row2(csr_src, hbs1, i, row_ptr[i], rend[i], halfe, lp2);
            float dv = dinv[i];
            pk = pack_bf2(fmaxf(fmaf(dv, s.x, b1v.x), 0.0f),
                          fmaxf(fmaf(dv, s.y, b1v.y), 0.0f));
        }
        if (lane < 32) {
            int blk = (lp >> 2) ^ (row & 7);   // 16B-block XOR swizzle (bank-conflict-free)
            *(unsigned*)&x1s[row * 64 + (blk << 3) + (lp2 & 7)] = pk;
        }
    }
    __syncthreads();

    if (wv < 2) {   // wv = n-tile index
        int half = lane >> 5;
        const uint4* wf = (const uint4*)w2frag;
        f32x16 acc;
#pragma unroll
        for (int r = 0; r < 16; ++r) acc[r] = 0.0f;
#pragma unroll
        for (int c = 0; c < 4; ++c) {
            Frag fa, fb;
            int blk = (c * 2 + half) ^ (lp & 7);
            fa.u4 = *(const uint4*)&x1s[lp * 64 + (blk << 3)];
            fb.u4 = wf[(c * 2 + wv) * 64 + lane];
            acc = __builtin_amdgcn_mfma_f32_32x32x16_bf16(fa.s8, fb.s8, acc, 0, 0, 0);
        }
#pragma unroll
        for (int r = 0; r < 16; ++r) {
            int m = (r & 3) + 8 * (r >> 2) + 4 * half;
            int i = n0 + m;
            if (i < n)
                hbs2[(size_t)i * HID + lp + 32 * wv] = __float2bfloat16(acc[r] * dinv[i]);
        }
    }
}

// ---------------- gather(layer2): xb = bf16(dv*sum + b2) ----------------
__global__ __launch_bounds__(256) void gather_out_kernel(
    const int* __restrict__ row_ptr, const int* __restrict__ rend,
    const int* __restrict__ csr_src, const float* __restrict__ dinv,
    const __hip_bfloat16* __restrict__ hbs2, const float* __restrict__ b2,
    __hip_bfloat16* __restrict__ xb, int n) {
    int t = threadIdx.x;
    int lane = t & 63;
    int halfe = lane >> 5;
    int lp = lane & 31;
    int lp2 = lp * 2;
    int i = blockIdx.x * 4 + (t >> 6);
    if (i >= n) return;
    float2 s = gather_row2(csr_src, hbs2, i, row_ptr[i], rend[i], halfe, lp2);
    if (lane < 32) {
        float dv = dinv[i];
        float2 b2v = *(const float2*)&b2[lp2];
        *(unsigned*)&xb[(size_t)i * HID + lp2] =
            pack_bf2(fmaf(dv, s.x, b2v.x), fmaf(dv, s.y, b2v.y));
    }
}

// ---------------- pair MLP head via MFMA, swapped operands + hoisted fragment loads ----------------
__global__ __launch_bounds__(256) void final_mfma_kernel(
    const int* __restrict__ pairs, const float* __restrict__ pf,
    const __hip_bfloat16* __restrict__ xb, const __hip_bfloat16* __restrict__ wfrag,
    const float4* __restrict__ wepi, const float* __restrict__ bf2,
    float* __restrict__ out, int p) {
    int lane = threadIdx.x & 63;
    int wid  = threadIdx.x >> 6;
    int half = lane >> 5;
    int lp   = lane & 31;

    float bf2r = bf2[0];
    const uint4* wf = (const uint4*)wfrag;

    int ngroups = (p + 31) >> 5;
    int nw = gridDim.x * 4;
    for (int g = blockIdx.x * 4 + wid; g < ngroups; g += nw) {
        int p32 = g << 5;
        int pi = p32 + lp; if (pi >= p) pi = p - 1;
        int2 pr = ((const int2*)pairs)[pi];
        const uint4* drow = (const uint4*)(xb + (size_t)pr.x * HID);
        const uint4* arow = (const uint4*)(xb + (size_t)pr.y * HID);

        uint4 du[4], au[4];
        float4 pflo, pfhi;
#pragma unroll
        for (int c = 0; c < 4; ++c) { du[c] = drow[c * 2 + half]; au[c] = arow[c * 2 + half]; }
        if (half == 0) {
            pflo = ((const float4*)pf)[pi * 2];
            pfhi = ((const float4*)pf)[pi * 2 + 1];
        }

        f32x16 acc0, acc1;
#pragma unroll
        for (int r = 0; r < 16; ++r) { acc0[r] = 0.0f; acc1[r] = 0.0f; }

#pragma unroll
        for (int c = 0; c < 4; ++c) {
            Frag fd, fx, fa, fb0, fb1;
            fd.u4 = du[c];
            fx.u4 = au[c];
#pragma unroll
            for (int q = 0; q < 4; ++q) fa.h2[q] = __hmul2(fd.h2[q], fx.h2[q]);
            fb0.u4 = wf[(c * 2 + 0) * 64 + lane];
            fb1.u4 = wf[(c * 2 + 1) * 64 + lane];
            acc0 = __builtin_amdgcn_mfma_f32_32x32x16_bf16(fb0.s8, fa.s8, acc0, 0, 0, 0);
            acc1 = __builtin_amdgcn_mfma_f32_32x32x16_bf16(fb1.s8, fa.s8, acc1, 0, 0, 0);
        }
        {   // chunk 4: patient features (k=64..71 real, 72..79 zero-pad)
            Frag fa, fb0, fb1;
            if (half == 0) {
                fa.h[0] = __float2bfloat16(pflo.x); fa.h[1] = __float2bfloat16(pflo.y);
                fa.h[2] = __float2bfloat16(pflo.z); fa.h[3] = __float2bfloat16(pflo.w);
                fa.h[4] = __float2bfloat16(pfhi.x); fa.h[5] = __float2bfloat16(pfhi.y);
                fa.h[6] = __float2bfloat16(pfhi.z); fa.h[7] = __float2bfloat16(pfhi.w);
            } else {
#pragma unroll
                for (int e = 0; e < 8; ++e) fa.us[e] = 0;
            }
            fb0.u4 = wf[8 * 64 + lane];
            fb1.u4 = wf[9 * 64 + lane];
            acc0 = __builtin_amdgcn_mfma_f32_32x32x16_bf16(fb0.s8, fa.s8, acc0, 0, 0, 0);
            acc1 = __builtin_amdgcn_mfma_f32_32x32x16_bf16(fb1.s8, fa.s8, acc1, 0, 0, 0);
        }

        float s = 0.0f;
#pragma unroll
        for (int r = 0; r < 16; ++r) {
            float4 wv = wepi[r * 2 + half];
            s += fmaxf(acc0[r] + wv.x, 0.0f) * wv.y
               + fmaxf(acc1[r] + wv.z, 0.0f) * wv.w;
        }
        s += __shfl_xor(s, 32, 64);
        if (lane < 32) {
            int po = p32 + lp;
            if (po < p) out[po] = 1.0f / (1.0f + expf(-(s + bf2r)));
        }
    }
}

extern "C" void kernel_launch(void* const* d_in, const int* in_sizes, int n_in,
                              void* d_out, int out_size, void* d_ws, size_t ws_size,
                              hipStream_t stream) {
    const int*   edge_index = (const int*)d_in[0];
    const int*   edge_pairs = (const int*)d_in[1];
    const float* pf         = (const float*)d_in[2];
    const float* emb        = (const float*)d_in[3];
    const float* W1         = (const float*)d_in[4];
    const float* b1         = (const float*)d_in[5];
    const float* W2         = (const float*)d_in[6];
    const float* b2         = (const float*)d_in[7];
    const float* Wf1        = (const float*)d_in[8];
    const float* bf1        = (const float*)d_in[9];
    const float* Wf2        = (const float*)d_in[10];
    const float* bf2        = (const float*)d_in[11];
    float*       out        = (float*)d_out;

    const int E = in_sizes[0] / 2;
    const int P = in_sizes[1] / 2;
    const int N = in_sizes[3] / EMB;
    const int NBUCK = (N + (1 << BSH) - 1) >> BSH;   // 196 for N=100k (<=NBMAX)

    char* ws = (char*)d_ws;
    size_t off = 0;
    float*          dinv    = (float*)(ws + off);          off += ((size_t)N * 4 + 255) & ~255ULL;
    __hip_bfloat16* hbs1    = (__hip_bfloat16*)(ws + off); off += ((size_t)N * HID * 2 + 255) & ~255ULL;
    __hip_bfloat16* hbs2    = (__hip_bfloat16*)(ws + off); off += ((size_t)N * HID * 2 + 255) & ~255ULL;
    __hip_bfloat16* xb      = (__hip_bfloat16*)(ws + off); off += ((size_t)N * HID * 2 + 255) & ~255ULL;
    __hip_bfloat16* wfrag   = (__hip_bfloat16*)(ws + off); off += ((size_t)10 * 512 * 2 + 255) & ~255ULL;
    __hip_bfloat16* w2frag  = (__hip_bfloat16*)(ws + off); off += ((size_t)8 * 512 * 2 + 255) & ~255ULL;
    float4*         wepi    = (float4*)(ws + off);         off += ((size_t)32 * 16 + 255) & ~255ULL;
    int*            row_ptr = (int*)(ws + off);            off += ((size_t)N * 4 + 255) & ~255ULL;
    int*            rend    = (int*)(ws + off);            off += ((size_t)N * 4 + 255) & ~255ULL;
    int*            btot    = (int*)(ws + off);            off += ((size_t)NBMAX * 4 + 255) & ~255ULL;
    int*            bbase   = (int*)(ws + off);            off += ((size_t)(NBMAX + 1) * 4 + 255) & ~255ULL;
    int*            bcur    = (int*)(ws + off);            off += ((size_t)NBMAX * 4 + 255) & ~255ULL;
    int*            csr_src = (int*)(ws + off);            off += ((size_t)E * 4 + 255) & ~255ULL;
    unsigned*       pairs2  = (unsigned*)(ws + off);       off += ((size_t)E * 4 + 255) & ~255ULL;
    (void)ws_size;

    const int EBLK = (E + CHUNK - 1) / CHUNK;

    // ---- CSR build (bucket hist -> scan -> partition -> bucket scatter) ----
    hipMemsetAsync(btot, 0, (size_t)NBMAX * 4, stream);
    bucket_hist_kernel<<<EBLK, 256, 0, stream>>>(edge_index + E, btot, E);
    prep_wf1_kernel<<<20, 256, 0, stream>>>(Wf1, wfrag);
    prep_w2_kernel<<<16, 256, 0, stream>>>(W2, w2frag);
    prep_epi_kernel<<<1, 32, 0, stream>>>(bf1, Wf2, wepi);
    scan_buckets_kernel<<<1, 256, 0, stream>>>(btot, bbase, bcur, NBUCK, E);
    partition_kernel<<<EBLK, 256, 0, stream>>>(edge_index, bcur, pairs2, E);
    bucket_scatter_kernel<<<NBUCK, 256, 0, stream>>>(bbase, pairs2, csr_src,
                                                     row_ptr, rend, dinv, N);

    // ---- layer 1: h1*dinv (bf16) ----
    mm1_kernel<<<(N + 3) / 4, 256, 0, stream>>>(emb, W1, dinv, hbs1, N);

    // ---- fused gather(L1) + MFMA mm2 -> hbs2 ----
    gather_mm2_kernel<<<(N + 31) / 32, 256, 0, stream>>>(row_ptr, rend, csr_src, dinv,
                                                         hbs1, w2frag, b1, hbs2, N);

    // ---- gather(L2) -> xb (b2 folded) ----
    gather_out_kernel<<<(N + 3) / 4, 256, 0, stream>>>(row_ptr, rend, csr_src, dinv,
                                                       hbs2, b2, xb, N);

    // ---- pair MLP head (MFMA, swapped operands) ----
    final_mfma_kernel<<<2048, 256, 0, stream>>>(edge_pairs, pf, xb, wfrag,
                                                wepi, bf2, out, P);
}

// Round 17
// 356.053 us; speedup vs baseline: 1.0235x; 1.0235x over previous
//
#include <hip/hip_runtime.h>
#include <hip/hip_bf16.h>
#include <math.h>

#define EMB 32
#define HID 64
#define PAT 8

#define BSH   9                 // nodes per bucket = 512
#define NBMAX 256               // max buckets supported (N <= 131072; src fits 17 bits)
#define CHUNK 4096              // edges per partition block

typedef __attribute__((ext_vector_type(8))) short short8v;   // 8 bf16 = 4 VGPRs
typedef __attribute__((ext_vector_type(16))) float f32x16;   // MFMA 32x32 accumulator

union Frag {
    short8v s8;
    uint4 u4;
    __hip_bfloat162 h2[4];
    __hip_bfloat16 h[8];
    unsigned short us[8];
};

__device__ __forceinline__ float bf_lo(unsigned v) { return __uint_as_float(v << 16); }
__device__ __forceinline__ float bf_hi(unsigned v) { return __uint_as_float(v & 0xFFFF0000u); }
__device__ __forceinline__ unsigned pack_bf2(float a, float b) {
    __hip_bfloat16 ba = __float2bfloat16(a), bb = __float2bfloat16(b);
    return ((unsigned)*(unsigned short*)&bb << 16) | *(unsigned short*)&ba;
}

// ---------------- pass 0: per-block LDS bucket histogram ----------------
__global__ __launch_bounds__(256) void bucket_hist_kernel(
    const int* __restrict__ dst, int* __restrict__ btot, int e) {
    __shared__ int cnt[NBMAX];
    int t = threadIdx.x;
    for (int k = t; k < NBMAX; k += 256) cnt[k] = 0;
    __syncthreads();
    int e0 = blockIdx.x * CHUNK;
    int ec = min(CHUNK, e - e0);
    for (int k = t; k < ec; k += 256)
        atomicAdd(&cnt[dst[e0 + k] >> BSH], 1);
    __syncthreads();
    for (int k = t; k < NBMAX; k += 256)
        if (cnt[k]) atomicAdd(&btot[k], cnt[k]);
}

// one block: exclusive scan of bucket totals -> bbase (197 entries), bcur
__global__ void scan_buckets_kernel(const int* __restrict__ btot, int* __restrict__ bbase,
                                    int* __restrict__ bcur, int nbuck, int e) {
    __shared__ int s[256];
    int t = threadIdx.x;
    int v = (t < nbuck) ? btot[t] : 0;
    s[t] = v;
    __syncthreads();
    for (int off = 1; off < 256; off <<= 1) {
        int u = (t >= off) ? s[t - off] : 0;
        __syncthreads();
        s[t] += u;
        __syncthreads();
    }
    if (t < nbuck) {
        int ex = s[t] - v;
        bbase[t] = ex;
        bcur[t]  = ex;
    }
    if (t == 0) bbase[nbuck] = e;
}

// ---------------- pass A: LDS-staged partition; output packed (dlocal<<17 | src) ----------------
__global__ __launch_bounds__(256) void partition_kernel(
    const int* __restrict__ ei, int* __restrict__ bcur,
    unsigned* __restrict__ pairs, int e) {
    __shared__ int cnt[NBMAX];
    __shared__ int scn[NBMAX];
    __shared__ int loff[NBMAX];
    __shared__ int base[NBMAX];
    __shared__ int2 stg[CHUNK];
    int t = threadIdx.x;
    int e0 = blockIdx.x * CHUNK;
    int ecnt = min(CHUNK, e - e0);

    int2 ed[CHUNK / 256];
#pragma unroll
    for (int j = 0; j < CHUNK / 256; ++j) {
        int k = t + j * 256;
        if (k < ecnt) { ed[j].x = ei[e0 + k]; ed[j].y = ei[e + e0 + k]; }
    }

    for (int k = t; k < NBMAX; k += 256) cnt[k] = 0;
    __syncthreads();
#pragma unroll
    for (int j = 0; j < CHUNK / 256; ++j)
        if (t + j * 256 < ecnt) atomicAdd(&cnt[ed[j].y >> BSH], 1);
    __syncthreads();
    int c = cnt[t];
    scn[t] = c;
    __syncthreads();
    for (int off = 1; off < 256; off <<= 1) {
        int u = (t >= off) ? scn[t - off] : 0;
        __syncthreads();
        scn[t] += u;
        __syncthreads();
    }
    int ex = scn[t] - c;
    __syncthreads();
    scn[t] = ex;
    loff[t] = ex;
    base[t] = c ? atomicAdd(&bcur[t], c) : 0;
    __syncthreads();
#pragma unroll
    for (int j = 0; j < CHUNK / 256; ++j)
        if (t + j * 256 < ecnt) {
            int pos = atomicAdd(&loff[ed[j].y >> BSH], 1);
            stg[pos] = ed[j];
        }
    __syncthreads();
    for (int k = t; k < ecnt; k += 256) {
        int2 pr = stg[k];
        int b = pr.y >> BSH;
        unsigned pk = ((unsigned)(pr.y & ((1 << BSH) - 1)) << 17) | (unsigned)pr.x;
        pairs[base[b] + (k - scn[b])] = pk;
    }
}

// ---------------- pass B: per-bucket count+scan+scatter; emits row_ptr/rend/dinv/csr_src ----------------
__global__ __launch_bounds__(256) void bucket_scatter_kernel(
    const int* __restrict__ bbase, const unsigned* __restrict__ pairs,
    int* __restrict__ csr_src, int* __restrict__ row_ptr, int* __restrict__ rend,
    float* __restrict__ dinv, int n) {
    __shared__ int cnt[1 << BSH];
    __shared__ int scn[256];
    __shared__ int cur[1 << BSH];
    int b = blockIdx.x;
    int n0 = b << BSH;
    int nn = min(1 << BSH, n - n0);
    int t = threadIdx.x;
    cnt[t] = 0; cnt[t + 256] = 0;
    __syncthreads();
    int p0 = bbase[b], p1 = bbase[b + 1];
    for (int k = p0 + t; k < p1; k += 256)
        atomicAdd(&cnt[pairs[k] >> 17], 1);
    __syncthreads();
    int ca = cnt[2 * t], cb = cnt[2 * t + 1];
    int c2 = ca + cb;
    scn[t] = c2;
    __syncthreads();
    for (int off = 1; off < 256; off <<= 1) {
        int u = (t >= off) ? scn[t - off] : 0;
        __syncthreads();
        scn[t] += u;
        __syncthreads();
    }
    int ex2 = scn[t] - c2;
    int ea = p0 + ex2;
    int eb = ea + ca;
    if (2 * t < nn) {
        row_ptr[n0 + 2 * t] = ea;
        rend[n0 + 2 * t]    = ea + ca;
        dinv[n0 + 2 * t]    = rsqrtf(1.0f + (float)ca);
        cur[2 * t] = ea;
    }
    if (2 * t + 1 < nn) {
        row_ptr[n0 + 2 * t + 1] = eb;
        rend[n0 + 2 * t + 1]    = eb + cb;
        dinv[n0 + 2 * t + 1]    = rsqrtf(1.0f + (float)cb);
        cur[2 * t + 1] = eb;
    }
    __syncthreads();
    for (int k = p0 + t; k < p1; k += 256) {
        unsigned v = pairs[k];
        int pos = atomicAdd(&cur[v >> 17], 1);
        csr_src[pos] = (int)(v & 0x1FFFFu);
    }
}

// ---------------- merged prep: Wf1 frags (10*512) + W2 frags (8*512) + epilogue (32) ----------------
__global__ void prep_all_kernel(const float* __restrict__ Wf1, const float* __restrict__ W2,
                                const float* __restrict__ bf1, const float* __restrict__ Wf2,
                                __hip_bfloat16* __restrict__ wfrag,
                                __hip_bfloat16* __restrict__ w2frag,
                                float4* __restrict__ wepi) {
    int gid = blockIdx.x * blockDim.x + threadIdx.x;
    if (gid < 10 * 512) {
        int f = gid >> 9, rem = gid & 511;
        int l = rem >> 3, e = rem & 7;
        int c = f >> 1, t = f & 1;
        int k = c * 16 + ((l >> 5) << 3) + e;
        int n = (l & 31) + (t << 5);
        float v = (k < HID + PAT) ? Wf1[k * 64 + n] : 0.0f;
        wfrag[gid] = __float2bfloat16(v);
    } else if (gid < 10 * 512 + 8 * 512) {
        int g = gid - 10 * 512;
        int f = g >> 9, rem = g & 511;
        int l = rem >> 3, e = rem & 7;
        int c = f >> 1, t = f & 1;
        int k = c * 16 + ((l >> 5) << 3) + e;
        int n = (l & 31) + (t << 5);
        w2frag[g] = __float2bfloat16(W2[k * 64 + n]);
    } else if (gid < 10 * 512 + 8 * 512 + 32) {
        int g = gid - (10 * 512 + 8 * 512);
        int r = g >> 1, half = g & 1;
        int ch = (r & 3) + 8 * (r >> 2) + 4 * half;
        wepi[g] = make_float4(bf1[ch], Wf2[ch], bf1[ch + 32], Wf2[ch + 32]);
    }
}

// ---------------- layer-1 matmul: hbs1 = bf16((emb @ W1) * dinv) ----------------
__global__ __launch_bounds__(256) void mm1_kernel(
    const float* __restrict__ emb, const float* __restrict__ W1,
    const float* __restrict__ dinv,
    __hip_bfloat16* __restrict__ hbs, int n) {
    __shared__ float w[EMB * HID];  // 8 KB
    int t = threadIdx.x;
    for (int k = t; k < EMB * HID; k += 256) w[k] = W1[k];
    __syncthreads();
    int wave = t >> 6, lane = t & 63;
    int i = blockIdx.x * 4 + wave;
    if (i >= n) return;
    float e = (lane < EMB) ? emb[i * EMB + lane] : 0.0f;
    float acc = 0.0f;
#pragma unroll
    for (int k = 0; k < EMB; ++k) {
        float ek = __shfl(e, k, 64);
        acc += ek * w[k * HID + lane];
    }
    hbs[(size_t)i * HID + lane] = __float2bfloat16(acc * dinv[i]);
}

// ======== 2-edges-per-instruction gather core (r13 exact form: VGPR-32, 61% occ, 86us) ========
// lane l: columns 2*(l&31), 2*(l&31)+1; lanes<32 even edges, lanes>=32 odd edges.
__device__ __forceinline__ float2 gather_row2(
    const int* __restrict__ csr_src, const __hip_bfloat16* __restrict__ hb,
    int i, int e, int end, int halfe, int lp2) {
    float s0 = 0.0f, s1 = 0.0f;
    int k = e + halfe;
    for (; k + 14 < end; k += 16) {
        int a0 = csr_src[k],      a1 = csr_src[k + 2],  a2 = csr_src[k + 4],  a3 = csr_src[k + 6];
        int a4 = csr_src[k + 8],  a5 = csr_src[k + 10], a6 = csr_src[k + 12], a7 = csr_src[k + 14];
        unsigned r0 = *(const unsigned*)&hb[(size_t)a0 * HID + lp2];
        unsigned r1 = *(const unsigned*)&hb[(size_t)a1 * HID + lp2];
        unsigned r2 = *(const unsigned*)&hb[(size_t)a2 * HID + lp2];
        unsigned r3 = *(const unsigned*)&hb[(size_t)a3 * HID + lp2];
        unsigned r4 = *(const unsigned*)&hb[(size_t)a4 * HID + lp2];
        unsigned r5 = *(const unsigned*)&hb[(size_t)a5 * HID + lp2];
        unsigned r6 = *(const unsigned*)&hb[(size_t)a6 * HID + lp2];
        unsigned r7 = *(const unsigned*)&hb[(size_t)a7 * HID + lp2];
        s0 += ((bf_lo(r0) + bf_lo(r1)) + (bf_lo(r2) + bf_lo(r3))) +
              ((bf_lo(r4) + bf_lo(r5)) + (bf_lo(r6) + bf_lo(r7)));
        s1 += ((bf_hi(r0) + bf_hi(r1)) + (bf_hi(r2) + bf_hi(r3))) +
              ((bf_hi(r4) + bf_hi(r5)) + (bf_hi(r6) + bf_hi(r7)));
    }
    for (; k + 6 < end; k += 8) {
        int a0 = csr_src[k], a1 = csr_src[k + 2], a2 = csr_src[k + 4], a3 = csr_src[k + 6];
        unsigned r0 = *(const unsigned*)&hb[(size_t)a0 * HID + lp2];
        unsigned r1 = *(const unsigned*)&hb[(size_t)a1 * HID + lp2];
        unsigned r2 = *(const unsigned*)&hb[(size_t)a2 * HID + lp2];
        unsigned r3 = *(const unsigned*)&hb[(size_t)a3 * HID + lp2];
        s0 += (bf_lo(r0) + bf_lo(r1)) + (bf_lo(r2) + bf_lo(r3));
        s1 += (bf_hi(r0) + bf_hi(r1)) + (bf_hi(r2) + bf_hi(r3));
    }
    for (; k < end; k += 2) {
        unsigned r0 = *(const unsigned*)&hb[(size_t)csr_src[k] * HID + lp2];
        s0 += bf_lo(r0);
        s1 += bf_hi(r0);
    }
    s0 += __shfl_xor(s0, 32, 64);
    s1 += __shfl_xor(s1, 32, 64);
    unsigned sv = *(const unsigned*)&hb[(size_t)i * HID + lp2];
    s0 += bf_lo(sv);
    s1 += bf_hi(sv);
    return make_float2(s0, s1);
}

// ---------------- fused gather(L1) + MFMA mm2: 32 rows/block ----------------
__global__ __launch_bounds__(256) void gather_mm2_kernel(
    const int* __restrict__ row_ptr, const int* __restrict__ rend,
    const int* __restrict__ csr_src, const float* __restrict__ dinv,
    const __hip_bfloat16* __restrict__ hbs1, const __hip_bfloat16* __restrict__ w2frag,
    const float* __restrict__ b1, __hip_bfloat16* __restrict__ hbs2, int n) {
    __shared__ __attribute__((aligned(16))) unsigned short x1s[32 * 64];  // 4 KB
    int t = threadIdx.x;
    int lane = t & 63;
    int wv = t >> 6;
    int halfe = lane >> 5;
    int lp = lane & 31;
    int lp2 = lp * 2;
    int n0 = blockIdx.x << 5;
    float2 b1v = *(const float2*)&b1[lp2];

    for (int rr = 0; rr < 8; ++rr) {
        int row = wv * 8 + rr;
        int i = n0 + row;
        unsigned pk = 0;
        if (i < n) {
            float2 s = gather_row2(csr_src, hbs1, i, row_ptr[i], rend[i], halfe, lp2);
            float dv = dinv[i];
            pk = pack_bf2(fmaxf(fmaf(dv, s.x, b1v.x), 0.0f),
                          fmaxf(fmaf(dv, s.y, b1v.y), 0.0f));
        }
        if (lane < 32) {
            int blk = (lp >> 2) ^ (row & 7);   // 16B-block XOR swizzle (bank-conflict-free)
            *(unsigned*)&x1s[row * 64 + (blk << 3) + (lp2 & 7)] = pk;
        }
    }
    __syncthreads();

    if (wv < 2) {   // wv = n-tile index
        int half = lane >> 5;
        const uint4* wf = (const uint4*)w2frag;
        f32x16 acc;
#pragma unroll
        for (int r = 0; r < 16; ++r) acc[r] = 0.0f;
#pragma unroll
        for (int c = 0; c < 4; ++c) {
            Frag fa, fb;
            int blk = (c * 2 + half) ^ (lp & 7);
            fa.u4 = *(const uint4*)&x1s[lp * 64 + (blk << 3)];
            fb.u4 = wf[(c * 2 + wv) * 64 + lane];
            acc = __builtin_amdgcn_mfma_f32_32x32x16_bf16(fa.s8, fb.s8, acc, 0, 0, 0);
        }
#pragma unroll
        for (int r = 0; r < 16; ++r) {
            int m = (r & 3) + 8 * (r >> 2) + 4 * half;
            int i = n0 + m;
            if (i < n)
                hbs2[(size_t)i * HID + lp + 32 * wv] = __float2bfloat16(acc[r] * dinv[i]);
        }
    }
}

// ---------------- gather(layer2): xb = bf16(dv*sum + b2) ----------------
__global__ __launch_bounds__(256) void gather_out_kernel(
    const int* __restrict__ row_ptr, const int* __restrict__ rend,
    const int* __restrict__ csr_src, const float* __restrict__ dinv,
    const __hip_bfloat16* __restrict__ hbs2, const float* __restrict__ b2,
    __hip_bfloat16* __restrict__ xb, int n) {
    int t = threadIdx.x;
    int lane = t & 63;
    int halfe = lane >> 5;
    int lp = lane & 31;
    int lp2 = lp * 2;
    int i = blockIdx.x * 4 + (t >> 6);
    if (i >= n) return;
    float2 s = gather_row2(csr_src, hbs2, i, row_ptr[i], rend[i], halfe, lp2);
    if (lane < 32) {
        float dv = dinv[i];
        float2 b2v = *(const float2*)&b2[lp2];
        *(unsigned*)&xb[(size_t)i * HID + lp2] =
            pack_bf2(fmaf(dv, s.x, b2v.x), fmaf(dv, s.y, b2v.y));
    }
}

// ---------------- pair MLP head via MFMA, swapped operands + hoisted fragment loads ----------------
__global__ __launch_bounds__(256) void final_mfma_kernel(
    const int* __restrict__ pairs, const float* __restrict__ pf,
    const __hip_bfloat16* __restrict__ xb, const __hip_bfloat16* __restrict__ wfrag,
    const float4* __restrict__ wepi, const float* __restrict__ bf2,
    float* __restrict__ out, int p) {
    int lane = threadIdx.x & 63;
    int wid  = threadIdx.x >> 6;
    int half = lane >> 5;
    int lp   = lane & 31;

    float bf2r = bf2[0];
    const uint4* wf = (const uint4*)wfrag;

    int ngroups = (p + 31) >> 5;
    int nw = gridDim.x * 4;
    for (int g = blockIdx.x * 4 + wid; g < ngroups; g += nw) {
        int p32 = g << 5;
        int pi = p32 + lp; if (pi >= p) pi = p - 1;
        int2 pr = ((const int2*)pairs)[pi];
        const uint4* drow = (const uint4*)(xb + (size_t)pr.x * HID);
        const uint4* arow = (const uint4*)(xb + (size_t)pr.y * HID);

        uint4 du[4], au[4];
        float4 pflo, pfhi;
#pragma unroll
        for (int c = 0; c < 4; ++c) { du[c] = drow[c * 2 + half]; au[c] = arow[c * 2 + half]; }
        if (half == 0) {
            pflo = ((const float4*)pf)[pi * 2];
            pfhi = ((const float4*)pf)[pi * 2 + 1];
        }

        f32x16 acc0, acc1;
#pragma unroll
        for (int r = 0; r < 16; ++r) { acc0[r] = 0.0f; acc1[r] = 0.0f; }

#pragma unroll
        for (int c = 0; c < 4; ++c) {
            Frag fd, fx, fa, fb0, fb1;
            fd.u4 = du[c];
            fx.u4 = au[c];
#pragma unroll
            for (int q = 0; q < 4; ++q) fa.h2[q] = __hmul2(fd.h2[q], fx.h2[q]);
            fb0.u4 = wf[(c * 2 + 0) * 64 + lane];
            fb1.u4 = wf[(c * 2 + 1) * 64 + lane];
            acc0 = __builtin_amdgcn_mfma_f32_32x32x16_bf16(fb0.s8, fa.s8, acc0, 0, 0, 0);
            acc1 = __builtin_amdgcn_mfma_f32_32x32x16_bf16(fb1.s8, fa.s8, acc1, 0, 0, 0);
        }
        {   // chunk 4: patient features (k=64..71 real, 72..79 zero-pad)
            Frag fa, fb0, fb1;
            if (half == 0) {
                fa.h[0] = __float2bfloat16(pflo.x); fa.h[1] = __float2bfloat16(pflo.y);
                fa.h[2] = __float2bfloat16(pflo.z); fa.h[3] = __float2bfloat16(pflo.w);
                fa.h[4] = __float2bfloat16(pfhi.x); fa.h[5] = __float2bfloat16(pfhi.y);
                fa.h[6] = __float2bfloat16(pfhi.z); fa.h[7] = __float2bfloat16(pfhi.w);
            } else {
#pragma unroll
                for (int e = 0; e < 8; ++e) fa.us[e] = 0;
            }
            fb0.u4 = wf[8 * 64 + lane];
            fb1.u4 = wf[9 * 64 + lane];
            acc0 = __builtin_amdgcn_mfma_f32_32x32x16_bf16(fb0.s8, fa.s8, acc0, 0, 0, 0);
            acc1 = __builtin_amdgcn_mfma_f32_32x32x16_bf16(fb1.s8, fa.s8, acc1, 0, 0, 0);
        }

        float s = 0.0f;
#pragma unroll
        for (int r = 0; r < 16; ++r) {
            float4 wv = wepi[r * 2 + half];
            s += fmaxf(acc0[r] + wv.x, 0.0f) * wv.y
               + fmaxf(acc1[r] + wv.z, 0.0f) * wv.w;
        }
        s += __shfl_xor(s, 32, 64);
        if (lane < 32) {
            int po = p32 + lp;
            if (po < p) out[po] = 1.0f / (1.0f + expf(-(s + bf2r)));
        }
    }
}

extern "C" void kernel_launch(void* const* d_in, const int* in_sizes, int n_in,
                              void* d_out, int out_size, void* d_ws, size_t ws_size,
                              hipStream_t stream) {
    const int*   edge_index = (const int*)d_in[0];
    const int*   edge_pairs = (const int*)d_in[1];
    const float* pf         = (const float*)d_in[2];
    const float* emb        = (const float*)d_in[3];
    const float* W1         = (const float*)d_in[4];
    const float* b1         = (const float*)d_in[5];
    const float* W2         = (const float*)d_in[6];
    const float* b2         = (const float*)d_in[7];
    const float* Wf1        = (const float*)d_in[8];
    const float* bf1        = (const float*)d_in[9];
    const float* Wf2        = (const float*)d_in[10];
    const float* bf2        = (const float*)d_in[11];
    float*       out        = (float*)d_out;

    const int E = in_sizes[0] / 2;
    const int P = in_sizes[1] / 2;
    const int N = in_sizes[3] / EMB;
    const int NBUCK = (N + (1 << BSH) - 1) >> BSH;   // 196 for N=100k (<=NBMAX)

    char* ws = (char*)d_ws;
    size_t off = 0;
    float*          dinv    = (float*)(ws + off);          off += ((size_t)N * 4 + 255) & ~255ULL;
    __hip_bfloat16* hbs1    = (__hip_bfloat16*)(ws + off); off += ((size_t)N * HID * 2 + 255) & ~255ULL;
    __hip_bfloat16* hbs2    = (__hip_bfloat16*)(ws + off); off += ((size_t)N * HID * 2 + 255) & ~255ULL;
    __hip_bfloat16* xb      = (__hip_bfloat16*)(ws + off); off += ((size_t)N * HID * 2 + 255) & ~255ULL;
    __hip_bfloat16* wfrag   = (__hip_bfloat16*)(ws + off); off += ((size_t)10 * 512 * 2 + 255) & ~255ULL;
    __hip_bfloat16* w2frag  = (__hip_bfloat16*)(ws + off); off += ((size_t)8 * 512 * 2 + 255) & ~255ULL;
    float4*         wepi    = (float4*)(ws + off);         off += ((size_t)32 * 16 + 255) & ~255ULL;
    int*            row_ptr = (int*)(ws + off);            off += ((size_t)N * 4 + 255) & ~255ULL;
    int*            rend    = (int*)(ws + off);            off += ((size_t)N * 4 + 255) & ~255ULL;
    int*            btot    = (int*)(ws + off);            off += ((size_t)NBMAX * 4 + 255) & ~255ULL;
    int*            bbase   = (int*)(ws + off);            off += ((size_t)(NBMAX + 1) * 4 + 255) & ~255ULL;
    int*            bcur    = (int*)(ws + off);            off += ((size_t)NBMAX * 4 + 255) & ~255ULL;
    int*            csr_src = (int*)(ws + off);            off += ((size_t)E * 4 + 255) & ~255ULL;
    unsigned*       pairs2  = (unsigned*)(ws + off);       off += ((size_t)E * 4 + 255) & ~255ULL;
    (void)ws_size;

    const int EBLK = (E + CHUNK - 1) / CHUNK;

    // ---- CSR build (bucket hist -> scan -> partition -> bucket scatter) ----
    hipMemsetAsync(btot, 0, (size_t)NBMAX * 4, stream);
    bucket_hist_kernel<<<EBLK, 256, 0, stream>>>(edge_index + E, btot, E);
    prep_all_kernel<<<(10 * 512 + 8 * 512 + 32 + 255) / 256, 256, 0, stream>>>(
        Wf1, W2, bf1, Wf2, wfrag, w2frag, wepi);
    scan_buckets_kernel<<<1, 256, 0, stream>>>(btot, bbase, bcur, NBUCK, E);
    partition_kernel<<<EBLK, 256, 0, stream>>>(edge_index, bcur, pairs2, E);
    bucket_scatter_kernel<<<NBUCK, 256, 0, stream>>>(bbase, pairs2, csr_src,
                                                     row_ptr, rend, dinv, N);

    // ---- layer 1: h1*dinv (bf16) ----
    mm1_kernel<<<(N + 3) / 4, 256, 0, stream>>>(emb, W1, dinv, hbs1, N);

    // ---- fused gather(L1) + MFMA mm2 -> hbs2 ----
    gather_mm2_kernel<<<(N + 31) / 32, 256, 0, stream>>>(row_ptr, rend, csr_src, dinv,
                                                         hbs1, w2frag, b1, hbs2, N);

    // ---- gather(L2) -> xb (b2 folded) ----
    gather_out_kernel<<<(N + 3) / 4, 256, 0, stream>>>(row_ptr, rend, csr_src, dinv,
                                                       hbs2, b2, xb, N);

    // ---- pair MLP head (MFMA, swapped operands) ----
    final_mfma_kernel<<<2048, 256, 0, stream>>>(edge_pairs, pf, xb, wfrag,
                                                wepi, bf2, out, P);
}